// Round 5
// baseline (206.937 us; speedup 1.0000x reference)
//
#include <hip/hip_runtime.h>

#define DIM   1024
#define HEADS 16
#define NSEQ  2048
#define BATCH 2

typedef unsigned short u16;
typedef unsigned long long u64;
typedef __attribute__((ext_vector_type(8))) short bf16x8;     // 8 bf16 = 4 VGPRs
typedef __attribute__((ext_vector_type(8))) _Float16 f16x8;   // 8 f16  = 4 VGPRs
typedef __attribute__((ext_vector_type(2))) __fp16 pkh2;      // cvt_pkrtz result type
typedef __attribute__((ext_vector_type(4))) float f32x4;
typedef __attribute__((ext_vector_type(16))) float f32x16;

__device__ __forceinline__ u16 f2b(float f) {
  union { float f; unsigned u; } v; v.f = f;
  unsigned r = (v.u + 0x7fffu + ((v.u >> 16) & 1u)) >> 16;  // RNE
  return (u16)r;
}

__device__ __forceinline__ u16 f2h(float f) {
  _Float16 h = (_Float16)f;                                 // v_cvt_f16_f32 (RNE)
  return __builtin_bit_cast(u16, h);
}

// async global->LDS, 16B per lane; LDS dest is wave-uniform base + lane*16
__device__ __forceinline__ void g2l16(const u16* g, u16* l) {
  __builtin_amdgcn_global_load_lds(
      (const __attribute__((address_space(1))) void*)g,
      (__attribute__((address_space(3))) void*)l, 16, 0, 0);
}

// ---------------------------------------------------------------- fp32 -> bf16
// elements with flat4-index < sc4 are scaled by s (folds softmax scale*log2e
// into the Q rows of w_qkv so exp2 args come out of QK^T free)
__global__ void cvt_bf16(const float* __restrict__ src, u16* __restrict__ dst,
                         int n4, int sc4, float s) {
  int i = blockIdx.x * blockDim.x + threadIdx.x;
  if (i < n4) {
    float4 f = ((const float4*)src)[i];
    float m = (i < sc4) ? s : 1.0f;
    union { u16 s[4]; u64 ll; } o;
    o.s[0] = f2b(f.x * m); o.s[1] = f2b(f.y * m);
    o.s[2] = f2b(f.z * m); o.s[3] = f2b(f.w * m);
    ((u64*)dst)[i] = o.ll;
  }
}

// ------------------------------------------------- C = A[M,K] @ Bt[N,K]^T (+bias)
// mode 0: f32 out + bias; mode 1: bf16 out; mode 2: qkv out (bf16 for n0<2048,
// f16 for the V third n0>=2048 — per-block uniform since 2048 % 128 == 0)
__global__ __launch_bounds__(256, 2)
void gemm_bt(const u16* __restrict__ A, const u16* __restrict__ Bt,
             void* __restrict__ C, const float* __restrict__ bias,
             int M, int Nc, int K, int mode) {
  __shared__ u16 As[128 * 64];
  __shared__ u16 Bs[128 * 64];
  const int tid  = threadIdx.x;
  const int wave = tid >> 6, lane = tid & 63;
  const int l15  = lane & 15, quad = lane >> 4;
  const int m0 = blockIdx.y * 128, n0 = blockIdx.x * 128;
  const int wm = (wave >> 1) * 64, wn = (wave & 1) * 64;
  const int rb = wave * 32;

  f32x4 acc[4][4] = {};

  for (int kt = 0; kt < K; kt += 64) {
#pragma unroll
    for (int c = 0; c < 4; ++c) {
      int r  = rb + c * 8 + (lane >> 3);
      int ck = (lane & 7) ^ (r & 7);
      g2l16(A  + (size_t)(m0 + r) * K + kt + ck * 8, &As[(rb + c * 8) * 64]);
      g2l16(Bt + (size_t)(n0 + r) * K + kt + ck * 8, &Bs[(rb + c * 8) * 64]);
    }
    __syncthreads();
#pragma unroll
    for (int ks = 0; ks < 2; ++ks) {
      bf16x8 a[4], b[4];
      int ch = ks * 4 + quad;
#pragma unroll
      for (int i = 0; i < 4; ++i) {
        int ra  = wm + i * 16 + l15;
        a[i] = *(const bf16x8*)&As[ra * 64 + ((ch ^ (ra & 7)) << 3)];
        int rb2 = wn + i * 16 + l15;
        b[i] = *(const bf16x8*)&Bs[rb2 * 64 + ((ch ^ (rb2 & 7)) << 3)];
      }
#pragma unroll
      for (int i = 0; i < 4; ++i)
#pragma unroll
        for (int j = 0; j < 4; ++j)
          acc[i][j] = __builtin_amdgcn_mfma_f32_16x16x32_bf16(a[i], b[j], acc[i][j], 0, 0, 0);
    }
    __syncthreads();
  }

  const int as_f16 = (mode == 2) && (n0 >= 2048);
#pragma unroll
  for (int i = 0; i < 4; ++i)
#pragma unroll
    for (int j = 0; j < 4; ++j) {
      int row = m0 + wm + i * 16 + quad * 4;
      int col = n0 + wn + j * 16 + l15;
#pragma unroll
      for (int r = 0; r < 4; ++r) {
        float v = acc[i][j][r];
        if (mode == 0) ((float*)C)[(size_t)(row + r) * Nc + col] = v + bias[col];
        else ((u16*)C)[(size_t)(row + r) * Nc + col] = as_f16 ? f2h(v) : f2b(v);
      }
    }
}

// --------------------------------------------------- flash attention v4
// 32x32x16 swapped-operand (S^T = K Q^T), lane owns q = lane&31 (32 q/wave).
// Fixed-max softmax (m=0). V stored f16 by the QKV GEMM; P packed with
// v_cvt_pkrtz; PV in f16 MFMA. V rows permuted in LDS so P C-layout packs
// directly into A-fragments (no shfl). Double-buffered K/V.
// grid: (B*H, N/128), 256 threads, 2 blocks/CU (64 KB LDS each).
__global__ __launch_bounds__(256, 2)
void attn(const u16* __restrict__ qkv, u16* __restrict__ outp) {
  __shared__ u16 Ks[2][128 * 64];    // K tile / Q staging, chunk-swizzle c^(row&7)
  __shared__ u16 Vts[2][64 * 128];   // permuted V^T (f16), swizzle c^((d+(d>>3))&15)
  const int tid  = threadIdx.x;
  const int wave = tid >> 6, lane = tid & 63;
  const int l31  = lane & 31, h = lane >> 5;
  const int b = blockIdx.x >> 4, hd = blockIdx.x & 15;
  const int q0 = blockIdx.y * 128;
  const u16* base = qkv + (size_t)b * NSEQ * 3072;
  const int qoff = hd * 64, koff = DIM + hd * 64, voff = 2 * DIM + hd * 64;
  const int dc = tid & 7, j0l = (tid >> 3) * 4;   // V staging: d-chunk, j-group
  const int vchunk = (j0l >> 4) * 2 + ((j0l >> 2) & 1);
  const int vboff  = 4 * ((j0l >> 3) & 1);

  union V4 { uint4 q; u16 s[8]; };
  union PA { unsigned w[4]; f16x8 f; };

  // ---- stage Q (128 rows) into Ks[0], pull B-fragments
#pragma unroll
  for (int c = 0; c < 4; ++c) {
    int bse = wave * 32 + c * 8;
    g2l16(base + (size_t)(q0 + bse + (lane >> 3)) * 3072 + qoff + (((lane & 7) ^ ((lane >> 3) & 7)) << 3),
          &Ks[0][bse * 64]);
  }
  __syncthreads();
  bf16x8 qf[4];
  {
    int qr = wave * 32 + l31;
#pragma unroll
    for (int kd = 0; kd < 4; ++kd)
      qf[kd] = *(const bf16x8*)&Ks[0][qr * 64 + (((kd * 2 + h) ^ (qr & 7)) << 3)];
  }
  __syncthreads();

  // ---- stage tile 0
  V4 vr[4];
#pragma unroll
  for (int c = 0; c < 4; ++c) {
    int bse = wave * 32 + c * 8;
    g2l16(base + (size_t)(bse + (lane >> 3)) * 3072 + koff + (((lane & 7) ^ ((lane >> 3) & 7)) << 3),
          &Ks[0][bse * 64]);
  }
#pragma unroll
  for (int e = 0; e < 4; ++e)
    vr[e].q = *(const uint4*)(base + (size_t)(j0l + e) * 3072 + voff + dc * 8);
#pragma unroll
  for (int u = 0; u < 8; ++u) {
    int d = dc * 8 + u;
    unsigned w0 = (unsigned)vr[0].s[u] | ((unsigned)vr[1].s[u] << 16);
    unsigned w1 = (unsigned)vr[2].s[u] | ((unsigned)vr[3].s[u] << 16);
    *(u64*)&Vts[0][d * 128 + ((vchunk ^ ((d + (d >> 3)) & 15)) << 3) + vboff] =
        (u64)w0 | ((u64)w1 << 32);
  }
  __syncthreads();

  float lrun = 0.0f;
  f32x16 oacc[2] = {};

  for (int t = 0; t < 16; ++t) {
    const int pbuf = t & 1;
    if (t < 15) {
      const int j0n = (t + 1) * 128;
#pragma unroll
      for (int c = 0; c < 4; ++c) {
        int bse = wave * 32 + c * 8;
        g2l16(base + (size_t)(j0n + bse + (lane >> 3)) * 3072 + koff + (((lane & 7) ^ ((lane >> 3) & 7)) << 3),
              &Ks[pbuf ^ 1][bse * 64]);
      }
#pragma unroll
      for (int e = 0; e < 4; ++e)
        vr[e].q = *(const uint4*)(base + (size_t)(j0n + j0l + e) * 3072 + voff + dc * 8);
    }

    // ---- S^T = K Q^T (exp2-ready logits)
    f32x16 sc[4] = {};
#pragma unroll
    for (int kd = 0; kd < 4; ++kd) {
      bf16x8 kb[4];
#pragma unroll
      for (int ni = 0; ni < 4; ++ni) {
        int kr = ni * 32 + l31;
        kb[ni] = *(const bf16x8*)&Ks[pbuf][kr * 64 + (((kd * 2 + h) ^ (kr & 7)) << 3)];
      }
#pragma unroll
      for (int ni = 0; ni < 4; ++ni)
        sc[ni] = __builtin_amdgcn_mfma_f32_32x32x16_bf16(kb[ni], qf[kd], sc[ni], 0, 0, 0);
    }

    // ---- exp2, l-accumulate, pack P into f16 A-fragments (pkrtz, no shfl)
    PA pa[8];
#pragma unroll
    for (int ni = 0; ni < 4; ++ni) {
      f32x16 p;
#pragma unroll
      for (int r = 0; r < 16; ++r) p[r] = __builtin_amdgcn_exp2f(sc[ni][r]);
      float s0 = (p[0] + p[1]) + (p[2] + p[3]);
      float s1 = (p[4] + p[5]) + (p[6] + p[7]);
      float s2 = (p[8] + p[9]) + (p[10] + p[11]);
      float s3 = (p[12] + p[13]) + (p[14] + p[15]);
      lrun += (s0 + s1) + (s2 + s3);
#pragma unroll
      for (int ks2 = 0; ks2 < 2; ++ks2)
#pragma unroll
        for (int i = 0; i < 4; ++i) {
          pkh2 t = __builtin_amdgcn_cvt_pkrtz(p[8 * ks2 + 2 * i], p[8 * ks2 + 2 * i + 1]);
          pa[2 * ni + ks2].w[i] = __builtin_bit_cast(unsigned, t);
        }
    }

    // ---- O += P V  (f16 MFMA; V rows pre-permuted to match pa's k-order)
#pragma unroll
    for (int f = 0; f < 8; ++f) {
      f16x8 vb[2];
#pragma unroll
      for (int nd = 0; nd < 2; ++nd) {
        int d = nd * 32 + l31;
        vb[nd] = *(const f16x8*)&Vts[pbuf][d * 128 + (((2 * f + h) ^ ((d + (d >> 3)) & 15)) << 3)];
      }
#pragma unroll
      for (int nd = 0; nd < 2; ++nd)
        oacc[nd] = __builtin_amdgcn_mfma_f32_32x32x16_f16(pa[f].f, vb[nd], oacc[nd], 0, 0, 0);
    }

    // ---- commit prefetched V
    if (t < 15) {
#pragma unroll
      for (int u = 0; u < 8; ++u) {
        int d = dc * 8 + u;
        unsigned w0 = (unsigned)vr[0].s[u] | ((unsigned)vr[1].s[u] << 16);
        unsigned w1 = (unsigned)vr[2].s[u] | ((unsigned)vr[3].s[u] << 16);
        *(u64*)&Vts[pbuf ^ 1][d * 128 + ((vchunk ^ ((d + (d >> 3)) & 15)) << 3) + vboff] =
            (u64)w0 | ((u64)w1 << 32);
      }
    }
    __syncthreads();
  }

  // ---- epilogue
  float linv = 1.0f / (lrun + __shfl_xor(lrun, 32, 64));
#pragma unroll
  for (int r = 0; r < 16; ++r) {
    int rowloc = (r & 3) + 8 * (r >> 2) + 4 * h;
    float lb = __shfl(linv, rowloc, 64);
    int row = q0 + wave * 32 + rowloc;
#pragma unroll
    for (int nd = 0; nd < 2; ++nd)
      outp[((size_t)b * NSEQ + row) * DIM + hd * 64 + nd * 32 + l31] = f2b(oacc[nd][r] * lb);
  }
}

extern "C" void kernel_launch(void* const* d_in, const int* in_sizes, int n_in,
                              void* d_out, int out_size, void* d_ws, size_t ws_size,
                              hipStream_t stream) {
  const float* x     = (const float*)d_in[0];
  const float* w_qkv = (const float*)d_in[1];
  const float* w_out = (const float*)d_in[2];
  const float* b_out = (const float*)d_in[3];
  float* outp = (float*)d_out;

  u16* xb    = (u16*)d_ws;                        // 4096*1024
  u16* wqkvb = xb    + (size_t)4096 * 1024;       // 3072*1024
  u16* woutb = wqkvb + (size_t)3072 * 1024;       // 1024*1024
  u16* qkvb  = woutb + (size_t)1024 * 1024;       // 4096*3072 (Q,K bf16 / V f16)
  u16* attnb = qkvb  + (size_t)4096 * 3072;       // 4096*1024

  const float C2 = 0.03125f * 1.44269504088896340736f;  // dim^-0.5 * log2(e)

  cvt_bf16<<<4096 * 1024 / 4 / 256, 256, 0, stream>>>(x,     xb,    4096 * 1024 / 4, 0, 1.0f);
  cvt_bf16<<<3072 * 1024 / 4 / 256, 256, 0, stream>>>(w_qkv, wqkvb, 3072 * 1024 / 4,
                                                      1024 * 1024 / 4, C2);
  cvt_bf16<<<1024 * 1024 / 4 / 256, 256, 0, stream>>>(w_out, woutb, 1024 * 1024 / 4, 0, 1.0f);

  gemm_bt<<<dim3(24, 32), 256, 0, stream>>>(xb, wqkvb, qkvb, nullptr, 4096, 3072, 1024, 2);
  attn<<<dim3(32, 16), 256, 0, stream>>>(qkvb, attnb);
  gemm_bt<<<dim3(8, 32), 256, 0, stream>>>(attnb, woutb, outp, b_out, 4096, 1024, 1024, 0);
}